// Round 5
// baseline (643.003 us; speedup 1.0000x reference)
//
#include <hip/hip_runtime.h>
#include <stddef.h>

#define BS 8192
#define NNODE 25
#define TT 128
#define LOG2E 1.4426950408889634f

typedef float v2f __attribute__((ext_vector_type(2)));

// Raw v_exp_f32 / v_rcp_f32. (__exp2f collides with glibc math.h macros.)
__device__ __forceinline__ float ex2(float x) { return __builtin_amdgcn_exp2f(x); }
__device__ __forceinline__ float rcp_(float x) { return __builtin_amdgcn_rcpf(x); }

// Static device buffers (no ws_size dependence). Fully rewritten every call.
__device__ float g_hf[NNODE * BS * 4];  // (i, b, d)
__device__ float g_hb[NNODE * BS * 4];

// Broadcast lane K of each quad (lanes 4q..4q+3) via DPP quad_perm — 1 VALU op.
template <int K>
__device__ __forceinline__ float bcast4(float v) {
  int s = __builtin_bit_cast(int, v);
  int r = __builtin_amdgcn_update_dpp(0, s, (K * 0x55), 0xF, 0xF, true);
  return __builtin_bit_cast(float, r);
}

// Packed gate accumulate: A(ig',fg') B(og',cc') += splat(s) * w.
__device__ __forceinline__ void acc2(v2f& A, v2f& B, float s, v2f wa, v2f wb) {
  v2f sv = {s, s};
  A = __builtin_elementwise_fma(sv, wa, A);
  B = __builtin_elementwise_fma(sv, wb, B);
}

// Full recurrence for one direction, dir as template param so the x float2
// component selection and neighbor-row mapping are compile-time.
template <int DIR>
__device__ __forceinline__ void rnn_run(
    int d, int b, const float* __restrict__ x,
    const float* __restrict__ h0, const float* __restrict__ c0,
    const float* __restrict__ Wx, const float* __restrict__ Wh,
    const float* __restrict__ Wn, const float* __restrict__ Bb,
    float* __restrict__ ho) {
  const int cI = d, cF = 4 + d, cO = 8 + d, cC = 12 + d;
  const float sS = -LOG2E, sC = 2.0f * LOG2E;

  // Packed prescaled weights. Input order k: 0=x, 1..4=h feats, 5..8=nb
  // [up,dn,lf,rt]. fwd rows [up,dn,lf,rt]=0,1,2,3; bwd order is [up,dn,rt,lf]
  // so lf-value uses row 3, rt-value row 2.
  v2f wA[9], wB[9];
  wA[0] = v2f{sS * Wx[cI], sS * Wx[cF]};
  wB[0] = v2f{sS * Wx[cO], sC * Wx[cC]};
#pragma unroll
  for (int k = 0; k < 4; ++k) {
    wA[1 + k] = v2f{sS * Wh[k * 16 + cI], sS * Wh[k * 16 + cF]};
    wB[1 + k] = v2f{sS * Wh[k * 16 + cO], sC * Wh[k * 16 + cC]};
  }
  const int nrow[4] = {0, 1, DIR ? 3 : 2, DIR ? 2 : 3};
#pragma unroll
  for (int k = 0; k < 4; ++k) {
    wA[5 + k] = v2f{sS * Wn[nrow[k] * 16 + cI], sS * Wn[nrow[k] * 16 + cF]};
    wB[5 + k] = v2f{sS * Wn[nrow[k] * 16 + cO], sC * Wn[nrow[k] * 16 + cC]};
  }
  const v2f bA = {sS * Bb[cI], sS * Bb[cF]};
  const v2f bB = {sS * Bb[cO], sC * Bb[cC]};

  float h[NNODE], c[NNODE], b3[NNODE];
#pragma unroll
  for (int i = 0; i < NNODE; ++i) {
    h[i] = h0[(i * BS + b) * 4 + d];
    c[i] = c0[(i * BS + b) * 4 + d];
    b3[i] = bcast4<3>(h[i]);
  }

  const float* xrow = x + (size_t)b * (NNODE * TT);

  for (int blk = 0; blk < TT / 2; ++blk) {
    // Direct float2 x loads from native (b,i,t) layout: 2 consecutive t,
    // 8B-aligned, offsets i*512B fit the 13-bit immediate (no addr VALU).
    // fwd block covers t = 2blk,2blk+1; bwd covers t = 127-2blk,126-2blk.
    const int tbase = DIR ? (TT - 2 - 2 * blk) : (2 * blk);
    v2f xv[NNODE];
#pragma unroll
    for (int i = 0; i < NNODE; ++i)
      xv[i] = *(const v2f*)(xrow + i * TT + tbase);

#pragma unroll
    for (int k = 0; k < 2; ++k) {
      // logical step s = 2blk+k; fwd uses component k, bwd component 1-k.
#pragma unroll
      for (int i = 0; i < NNODE; ++i) {
        const float xval =
            (((DIR ? (1 - k) : k) == 0) ? xv[i].x : xv[i].y);
        // Own features 0..2 via quad broadcast; feature 3 via b3[].
        const float f0 = bcast4<0>(h[i]);
        const float f1 = bcast4<1>(h[i]);
        const float f2 = bcast4<2>(h[i]);

        v2f A = bA, B = bB;
        acc2(A, B, xval, wA[0], wB[0]);
        acc2(A, B, f0, wA[1], wB[1]);
        acc2(A, B, f1, wA[2], wB[2]);
        acc2(A, B, f2, wA[3], wB[3]);
        acc2(A, B, b3[i], wA[4], wB[4]);
        // up/lf updated this t (j<i), dn/rt prev-t (j>i). Out-of-range terms
        // are exact zeros -> statically skipped. lf/rt row-wrap faithful.
        if (i >= 5) acc2(A, B, b3[i - 5], wA[5], wB[5]);  // up
        if (i < 20) acc2(A, B, b3[i + 5], wA[6], wB[6]);  // dn
        if (i >= 1) acc2(A, B, b3[i - 1], wA[7], wB[7]);  // lf (serial dep)
        if (i < 24) acc2(A, B, b3[i + 1], wA[8], wB[8]);  // rt

        // A = (-log2e*ig, -log2e*fg), B = (-log2e*og, 2log2e*cc)
        const float Ei = ex2(A.x);  // e^-ig
        const float Ef = ex2(A.y);  // e^-fg
        const float Eo = ex2(B.x);  // e^-og
        const float Ec = ex2(B.y);  // e^{2cc}
        // nc = c/(1+Ef) + (Ec-1)/((1+Ei)(Ec+1)), single rcp:
        const float Di = 1.0f + Ei;
        const float Df = 1.0f + Ef;
        const float P = Di * (Ec + 1.0f);
        const float num = fmaf(c[i], P, (Ec - 1.0f) * Df);
        const float nc = num * rcp_(Df * P);
        // h = sigmoid(og)*tanh(nc) = (1-En)/((1+En)(1+Eo)), single rcp:
        const float En = ex2(-2.0f * LOG2E * nc);
        const float hn = (1.0f - En) * rcp_((1.0f + En) * (1.0f + Eo));
        c[i] = nc;
        h[i] = hn;
        b3[i] = bcast4<3>(hn);
      }
    }
  }

#pragma unroll
  for (int i = 0; i < NNODE; ++i) ho[(i * BS + b) * 4 + d] = h[i];
}

// Quad scheme: 4 lanes per (batch, dir) chain; lane d owns feature d and gate
// cols {d,4+d,8+d,12+d}. grid (128, 2) x block 256 -> 1024 waves = 1/SIMD.
__global__ __launch_bounds__(256, 1) void rnn_kernel(
    const float* __restrict__ x,
    const float* __restrict__ h0f, const float* __restrict__ c0f,
    const float* __restrict__ h0b, const float* __restrict__ c0b,
    const float* __restrict__ Wxf, const float* __restrict__ Whf,
    const float* __restrict__ Wnf, const float* __restrict__ bf,
    const float* __restrict__ Wxb, const float* __restrict__ Whb,
    const float* __restrict__ Wnb, const float* __restrict__ bb_) {
  const int d = threadIdx.x & 3;
  const int b = blockIdx.x * 64 + (threadIdx.x >> 2);
  if (blockIdx.y == 0) {
    rnn_run<0>(d, b, x, h0f, c0f, Wxf, Whf, Wnf, bf, g_hf);
  } else {
    rnn_run<1>(d, b, x, h0b, c0b, Wxb, Whb, Wnb, bb_, g_hb);
  }
}

// H(b,200) -> sigmoid(H@Wff+bff) -> softmax(ff@Wout+bout).
__global__ __launch_bounds__(128) void ff_kernel(
    const float* __restrict__ Wff, const float* __restrict__ bff,
    const float* __restrict__ Wout, const float* __restrict__ bout,
    float* __restrict__ out) {
  __shared__ float Hs[8][200];
  __shared__ float ffs[8][129];
  const int tid = threadIdx.x;
  const int b0 = blockIdx.x * 8;

  for (int idx = tid; idx < 8 * 200; idx += 128) {
    const int bb = idx / 200;
    const int k = idx - bb * 200;
    const int i = k >> 3;
    const int dd = k & 7;
    const int b = b0 + bb;
    Hs[bb][k] = (dd < 4) ? g_hf[(i * BS + b) * 4 + dd]
                         : g_hb[(i * BS + b) * 4 + (dd - 4)];
  }
  __syncthreads();

  float acc[8];
  const float bv = bff[tid];
#pragma unroll
  for (int bb = 0; bb < 8; ++bb) acc[bb] = bv;
  for (int k = 0; k < 200; ++k) {
    const float w = Wff[k * 128 + tid];
#pragma unroll
    for (int bb = 0; bb < 8; ++bb) acc[bb] = fmaf(Hs[bb][k], w, acc[bb]);
  }
#pragma unroll
  for (int bb = 0; bb < 8; ++bb)
    ffs[bb][tid] = rcp_(1.0f + ex2(-LOG2E * acc[bb]));
  __syncthreads();

  if (tid < 8) {
    float z0 = bout[0], z1 = bout[1];
    for (int n = 0; n < 128; ++n) {
      const float f = ffs[tid][n];
      z0 = fmaf(f, Wout[n * 2 + 0], z0);
      z1 = fmaf(f, Wout[n * 2 + 1], z1);
    }
    const float m = fmaxf(z0, z1);
    const float e0 = ex2(LOG2E * (z0 - m)), e1 = ex2(LOG2E * (z1 - m));
    const float s = rcp_(e0 + e1);
    out[(size_t)(b0 + tid) * 2 + 0] = e0 * s;
    out[(size_t)(b0 + tid) * 2 + 1] = e1 * s;
  }
}

extern "C" void kernel_launch(void* const* d_in, const int* in_sizes, int n_in,
                              void* d_out, int out_size, void* d_ws, size_t ws_size,
                              hipStream_t stream) {
  (void)in_sizes; (void)n_in; (void)out_size; (void)d_ws; (void)ws_size;
  const float* x    = (const float*)d_in[0];
  const float* h0f  = (const float*)d_in[1];
  const float* c0f  = (const float*)d_in[2];
  const float* h0b  = (const float*)d_in[3];
  const float* c0b  = (const float*)d_in[4];
  const float* Wxf  = (const float*)d_in[5];
  const float* Whf  = (const float*)d_in[6];
  const float* Wnf  = (const float*)d_in[7];
  const float* bf   = (const float*)d_in[8];
  const float* Wxb  = (const float*)d_in[9];
  const float* Whb  = (const float*)d_in[10];
  const float* Wnb  = (const float*)d_in[11];
  const float* bb   = (const float*)d_in[12];
  const float* Wff  = (const float*)d_in[13];
  const float* bff  = (const float*)d_in[14];
  const float* Wout = (const float*)d_in[15];
  const float* bout = (const float*)d_in[16];
  float* out = (float*)d_out;

  rnn_kernel<<<dim3(128, 2), dim3(256), 0, stream>>>(
      x, h0f, c0f, h0b, c0b, Wxf, Whf, Wnf, bf, Wxb, Whb, Wnb, bb);
  ff_kernel<<<dim3(1024), dim3(128), 0, stream>>>(Wff, bff, Wout, bout, out);
}

// Round 7
// 580.455 us; speedup vs baseline: 1.1078x; 1.1078x over previous
//
#include <hip/hip_runtime.h>
#include <stddef.h>

#define BS 8192
#define NNODE 25
#define TT 128
#define TCH 16                 // t-steps per staged LDS window
#define NW (TT / TCH)          // 8 windows
#define XPAD 65                // chain-dim stride: 65 = 64+1 -> bank spread
#define LOG2E 1.4426950408889634f

typedef float v2f __attribute__((ext_vector_type(2)));
typedef float v4f __attribute__((ext_vector_type(4)));

// Raw v_exp_f32 / v_rcp_f32. (__exp2f collides with glibc math.h macros.)
__device__ __forceinline__ float ex2(float x) { return __builtin_amdgcn_exp2f(x); }
__device__ __forceinline__ float rcp_(float x) { return __builtin_amdgcn_rcpf(x); }

// Static device buffers (no ws_size dependence). Fully rewritten every call.
__device__ float g_hf[NNODE * BS * 4];  // (i, b, d)
__device__ float g_hb[NNODE * BS * 4];

// Broadcast lane K of each quad (lanes 4q..4q+3) via DPP quad_perm — 1 VALU op.
template <int K>
__device__ __forceinline__ float bcast4(float v) {
  int s = __builtin_bit_cast(int, v);
  int r = __builtin_amdgcn_update_dpp(0, s, (K * 0x55), 0xF, 0xF, true);
  return __builtin_bit_cast(float, r);
}

// Packed gate accumulate: A(ig',fg') B(og',cc') += splat(s) * w.
__device__ __forceinline__ void acc2(v2f& A, v2f& B, float s, v2f wa, v2f wb) {
  v2f sv = {s, s};
  A = __builtin_elementwise_fma(sv, wa, A);
  B = __builtin_elementwise_fma(sv, wb, B);
}

// Full recurrence for one direction; DIR compile-time so staging index math
// and neighbor-row mapping are static. Block = 256 threads = 64 chains.
template <int DIR>
__device__ __forceinline__ void rnn_run(
    int tid, const float* __restrict__ xblk, float* __restrict__ xs,
    const float* __restrict__ h0, const float* __restrict__ c0,
    const float* __restrict__ Wx, const float* __restrict__ Wh,
    const float* __restrict__ Wn, const float* __restrict__ Bb,
    float* __restrict__ ho, int b) {
  const int d = tid & 3;
  const int bl = tid >> 2;  // local chain 0..63
  const int cI = d, cF = 4 + d, cO = 8 + d, cC = 12 + d;
  const float sS = -LOG2E, sC = 2.0f * LOG2E;

  // Packed prescaled weights. Input order k: 0=x, 1..4=h feats, 5..8=nb
  // [up,dn,lf,rt]. fwd rows [up,dn,lf,rt]=0,1,2,3; bwd order is [up,dn,rt,lf]
  // so lf-value uses row 3, rt-value row 2.
  v2f wA[9], wB[9];
  wA[0] = v2f{sS * Wx[cI], sS * Wx[cF]};
  wB[0] = v2f{sS * Wx[cO], sC * Wx[cC]};
#pragma unroll
  for (int k = 0; k < 4; ++k) {
    wA[1 + k] = v2f{sS * Wh[k * 16 + cI], sS * Wh[k * 16 + cF]};
    wB[1 + k] = v2f{sS * Wh[k * 16 + cO], sC * Wh[k * 16 + cC]};
  }
  const int nrow[4] = {0, 1, DIR ? 3 : 2, DIR ? 2 : 3};
#pragma unroll
  for (int k = 0; k < 4; ++k) {
    wA[5 + k] = v2f{sS * Wn[nrow[k] * 16 + cI], sS * Wn[nrow[k] * 16 + cF]};
    wB[5 + k] = v2f{sS * Wn[nrow[k] * 16 + cO], sC * Wn[nrow[k] * 16 + cC]};
  }
  const v2f bA = {sS * Bb[cI], sS * Bb[cF]};
  const v2f bB = {sS * Bb[cO], sC * Bb[cC]};

  float h[NNODE], c[NNODE], b3[NNODE];
#pragma unroll
  for (int i = 0; i < NNODE; ++i) {
    h[i] = h0[(i * BS + b) * 4 + d];
    c[i] = c0[(i * BS + b) * 4 + d];
    b3[i] = bcast4<3>(h[i]);
  }

  const int t4 = tid & 3;
  const int s0 = tid >> 2;

  for (int w = 0; w < NW; ++w) {
    __syncthreads();  // previous window's reads complete before overwrite
    // Stage window w: logical steps s=16w..16w+15 (bwd: t = 127-s).
    // Each thread: 25 float4 global loads (64B-aligned segments, every byte
    // consumed) -> 100 scalar LDS writes into xs[kk][i][bl] (stride XPAD).
#pragma unroll
    for (int r = 0; r < NNODE; ++r) {
      const int seg = s0 + 64 * r;       // 0..1599
      const int sbl = seg / 25;          // chain
      const int sii = seg - sbl * 25;    // node
      const int tb = (DIR ? (TT - TCH - TCH * w) : (TCH * w)) + 4 * t4;
      const v4f v = *(const v4f*)(xblk + ((size_t)sbl * NNODE + sii) * TT + tb);
#pragma unroll
      for (int j = 0; j < 4; ++j) {
        const int kk = DIR ? (15 - 4 * t4 - j) : (4 * t4 + j);
        xs[(kk * NNODE + sii) * XPAD + sbl] = v[j];
      }
    }
    __syncthreads();

#pragma unroll 1  // keep I$ small: body is the unrolled 25-node step
    for (int kk = 0; kk < TCH; ++kk) {
      // Batch the 25 x reads (quad-broadcast, conflict-free across quads).
      float xq[NNODE];
#pragma unroll
      for (int i = 0; i < NNODE; ++i) xq[i] = xs[(kk * NNODE + i) * XPAD + bl];

#pragma unroll
      for (int i = 0; i < NNODE; ++i) {
        // Own features 0..2 via quad broadcast; feature 3 via b3[].
        const float f0 = bcast4<0>(h[i]);
        const float f1 = bcast4<1>(h[i]);
        const float f2 = bcast4<2>(h[i]);

        v2f A = bA, B = bB;
        acc2(A, B, xq[i], wA[0], wB[0]);
        acc2(A, B, f0, wA[1], wB[1]);
        acc2(A, B, f1, wA[2], wB[2]);
        acc2(A, B, f2, wA[3], wB[3]);
        acc2(A, B, b3[i], wA[4], wB[4]);
        // up/lf updated this t (j<i), dn/rt prev-t (j>i). Out-of-range terms
        // are exact zeros -> statically skipped. lf/rt row-wrap faithful.
        if (i >= 5) acc2(A, B, b3[i - 5], wA[5], wB[5]);  // up
        if (i < 20) acc2(A, B, b3[i + 5], wA[6], wB[6]);  // dn
        if (i >= 1) acc2(A, B, b3[i - 1], wA[7], wB[7]);  // lf (serial dep)
        if (i < 24) acc2(A, B, b3[i + 1], wA[8], wB[8]);  // rt

        // A = (-log2e*ig, -log2e*fg), B = (-log2e*og, 2log2e*cc)
        const float Ei = ex2(A.x);  // e^-ig
        const float Ef = ex2(A.y);  // e^-fg
        const float Eo = ex2(B.x);  // e^-og
        const float Ec = ex2(B.y);  // e^{2cc}
        // nc = c/(1+Ef) + (Ec-1)/((1+Ei)(Ec+1)), single rcp:
        const float Di = 1.0f + Ei;
        const float Df = 1.0f + Ef;
        const float P = Di * (Ec + 1.0f);
        const float num = fmaf(c[i], P, (Ec - 1.0f) * Df);
        const float nc = num * rcp_(Df * P);
        // h = sigmoid(og)*tanh(nc) = (1-En)/((1+En)(1+Eo)), single rcp:
        const float En = ex2(-2.0f * LOG2E * nc);
        const float hn = (1.0f - En) * rcp_((1.0f + En) * (1.0f + Eo));
        c[i] = nc;
        h[i] = hn;
        b3[i] = bcast4<3>(hn);
      }
    }
  }

#pragma unroll
  for (int i = 0; i < NNODE; ++i) ho[(i * BS + b) * 4 + d] = h[i];
}

// Quad scheme: 4 lanes per (batch, dir) chain; lane d owns feature d and gate
// cols {d,4+d,8+d,12+d}. grid (128, 2) x block 256 -> 1024 waves = 1/SIMD,
// 256 blocks = 1 block/CU (LDS 104 KB caps it there anyway).
__global__ __launch_bounds__(256, 1) void rnn_kernel(
    const float* __restrict__ x,
    const float* __restrict__ h0f, const float* __restrict__ c0f,
    const float* __restrict__ h0b, const float* __restrict__ c0b,
    const float* __restrict__ Wxf, const float* __restrict__ Whf,
    const float* __restrict__ Wnf, const float* __restrict__ bf,
    const float* __restrict__ Wxb, const float* __restrict__ Whb,
    const float* __restrict__ Wnb, const float* __restrict__ bb_) {
  __shared__ float xs[TCH * NNODE * XPAD];  // 104,000 B
  const int tid = threadIdx.x;
  const int b = blockIdx.x * 64 + (tid >> 2);
  const float* xblk = x + (size_t)(blockIdx.x * 64) * (NNODE * TT);
  if (blockIdx.y == 0) {
    rnn_run<0>(tid, xblk, xs, h0f, c0f, Wxf, Whf, Wnf, bf, g_hf, b);
  } else {
    rnn_run<1>(tid, xblk, xs, h0b, c0b, Wxb, Whb, Wnb, bb_, g_hb, b);
  }
}

// H(b,200) -> sigmoid(H@Wff+bff) -> softmax(ff@Wout+bout).
__global__ __launch_bounds__(128) void ff_kernel(
    const float* __restrict__ Wff, const float* __restrict__ bff,
    const float* __restrict__ Wout, const float* __restrict__ bout,
    float* __restrict__ out) {
  __shared__ float Hs[8][200];
  __shared__ float ffs[8][129];
  const int tid = threadIdx.x;
  const int b0 = blockIdx.x * 8;

  for (int idx = tid; idx < 8 * 200; idx += 128) {
    const int bb = idx / 200;
    const int k = idx - bb * 200;
    const int i = k >> 3;
    const int dd = k & 7;
    const int b = b0 + bb;
    Hs[bb][k] = (dd < 4) ? g_hf[(i * BS + b) * 4 + dd]
                         : g_hb[(i * BS + b) * 4 + (dd - 4)];
  }
  __syncthreads();

  float acc[8];
  const float bv = bff[tid];
#pragma unroll
  for (int bb = 0; bb < 8; ++bb) acc[bb] = bv;
  for (int k = 0; k < 200; ++k) {
    const float w = Wff[k * 128 + tid];
#pragma unroll
    for (int bb = 0; bb < 8; ++bb) acc[bb] = fmaf(Hs[bb][k], w, acc[bb]);
  }
#pragma unroll
  for (int bb = 0; bb < 8; ++bb)
    ffs[bb][tid] = rcp_(1.0f + ex2(-LOG2E * acc[bb]));
  __syncthreads();

  if (tid < 8) {
    float z0 = bout[0], z1 = bout[1];
    for (int n = 0; n < 128; ++n) {
      const float f = ffs[tid][n];
      z0 = fmaf(f, Wout[n * 2 + 0], z0);
      z1 = fmaf(f, Wout[n * 2 + 1], z1);
    }
    const float m = fmaxf(z0, z1);
    const float e0 = ex2(LOG2E * (z0 - m)), e1 = ex2(LOG2E * (z1 - m));
    const float s = rcp_(e0 + e1);
    out[(size_t)(b0 + tid) * 2 + 0] = e0 * s;
    out[(size_t)(b0 + tid) * 2 + 1] = e1 * s;
  }
}

extern "C" void kernel_launch(void* const* d_in, const int* in_sizes, int n_in,
                              void* d_out, int out_size, void* d_ws, size_t ws_size,
                              hipStream_t stream) {
  (void)in_sizes; (void)n_in; (void)out_size; (void)d_ws; (void)ws_size;
  const float* x    = (const float*)d_in[0];
  const float* h0f  = (const float*)d_in[1];
  const float* c0f  = (const float*)d_in[2];
  const float* h0b  = (const float*)d_in[3];
  const float* c0b  = (const float*)d_in[4];
  const float* Wxf  = (const float*)d_in[5];
  const float* Whf  = (const float*)d_in[6];
  const float* Wnf  = (const float*)d_in[7];
  const float* bf   = (const float*)d_in[8];
  const float* Wxb  = (const float*)d_in[9];
  const float* Whb  = (const float*)d_in[10];
  const float* Wnb  = (const float*)d_in[11];
  const float* bb   = (const float*)d_in[12];
  const float* Wff  = (const float*)d_in[13];
  const float* bff  = (const float*)d_in[14];
  const float* Wout = (const float*)d_in[15];
  const float* bout = (const float*)d_in[16];
  float* out = (float*)d_out;

  rnn_kernel<<<dim3(128, 2), dim3(256), 0, stream>>>(
      x, h0f, c0f, h0b, c0b, Wxf, Whf, Wnf, bf, Wxb, Whb, Wnb, bb);
  ff_kernel<<<dim3(1024), dim3(128), 0, stream>>>(Wff, bff, Wout, bout, out);
}